// Round 10
// baseline (86.052 us; speedup 1.0000x reference)
//
#include <hip/hip_runtime.h>
#include <cstdint>

typedef unsigned int u32;
typedef unsigned long long u64;

constexpr int B_ = 8;
constexpr int P_ = 16384;
constexpr int K_ = 100;
constexpr int M_ = P_ * 4;            // candidates per image, j = p*4+(cls-1)
constexpr int TSEL = 192;             // selection target
constexpr int CAP = 256;              // selection capacity (= one resolve chunk)
constexpr int NBP = 576;              // hist bins: (bits>>16) - BASE16
constexpr u32 BASE16 = 0x3D4Cu;       // bits(0.05f) >> 16
constexpr float SCORE_T = 0.05f;
constexpr float CLIPV = 4.135166556742356f;  // log(1000/16)

// swizzled candidate slot: rotate low-6 bits by 4*(group) -> the 4 simultaneous
// row-group reads in the pairwise phase hit 2 banks (2-way == free) not 4-way.
__device__ inline int aphys(int i) {
  return (i < CAP) ? ((((i & 63) + ((i >> 6) << 2)) & 63) | (i & 192)) : i;
}

// decode + clip, reference op order (bit-identical everywhere it's used)
__device__ inline float4 decode_clip(float4 rel, float4 pr, float Wf, float Hf) {
  const float w  = pr.z - pr.x;
  const float h  = pr.w - pr.y;
  const float cx = pr.x + 0.5f * w;
  const float cy = pr.y + 0.5f * h;
  const float dx = rel.x / 10.0f;
  const float dy = rel.y / 10.0f;
  const float dw = fminf(rel.z / 5.0f, CLIPV);
  const float dh = fminf(rel.w / 5.0f, CLIPV);
  const float pcx = dx * w + cx;
  const float pcy = dy * h + cy;
  const float pw = expf(dw) * w;
  const float ph = expf(dh) * h;
  float x1 = pcx - 0.5f * pw, y1 = pcy - 0.5f * ph;
  float x2 = pcx + 0.5f * pw, y2 = pcy + 0.5f * ph;
  x1 = fminf(fmaxf(x1, 0.f), Wf);
  x2 = fminf(fmaxf(x2, 0.f), Wf);
  y1 = fminf(fmaxf(y1, 0.f), Hf);
  y2 = fminf(fmaxf(y2, 0.f), Hf);
  return make_float4(x1, y1, x2, y2);
}

// ---------------------------------------------------------------------------
// Kernel 1 (wide, 512 blocks, image-pure): softmax + decode (for max coord
// only; boxes NOT stored) + scores store + per-block LDS hist -> plain flush.
// ---------------------------------------------------------------------------
__global__ __launch_bounds__(256) void prep_kernel(
    const float* __restrict__ logits,     // [N,5]
    const float* __restrict__ boxreg,     // [N,20]
    const float* __restrict__ props,      // [N,4]
    const int*  __restrict__ image_hw,    // {H,W}
    float* __restrict__ wscores,          // [B*M]
    float* __restrict__ wblockmax,        // [512]
    u32*   __restrict__ bhist)            // [512][NBP]
{
  __shared__ u32 lh[NBP];
  __shared__ float red[256];
  for (int i = threadIdx.x; i < NBP; i += 256) lh[i] = 0u;
  __syncthreads();

  const int n = blockIdx.x * 256 + threadIdx.x;   // 512*256 == B*P

  float l[5];
#pragma unroll
  for (int i = 0; i < 5; ++i) l[i] = logits[n * 5 + i];
  float mx = l[0];
#pragma unroll
  for (int i = 1; i < 5; ++i) mx = fmaxf(mx, l[i]);
  float e[5]; float ssum = 0.f;
#pragma unroll
  for (int i = 0; i < 5; ++i) { e[i] = expf(l[i] - mx); ssum += e[i]; }

  const float4 pr = reinterpret_cast<const float4*>(props)[n];
  const float Hf = (float)image_hw[0];
  const float Wf = (float)image_hw[1];

  float bmax = 0.f;
  float sc[4];
#pragma unroll
  for (int c = 1; c < 5; ++c) {
    const float4 rel = reinterpret_cast<const float4*>(boxreg)[n * 5 + c];
    const float4 bx = decode_clip(rel, pr, Wf, Hf);
    bmax = fmaxf(bmax, fmaxf(fmaxf(bx.x, bx.z), fmaxf(bx.y, bx.w)));
    const float sv = e[c] / ssum;
    sc[c - 1] = sv;
    if (sv > SCORE_T) {
      u32 bin = (__float_as_uint(sv) >> 16) - BASE16;
      if (bin >= (u32)NBP) bin = NBP - 1;
      atomicAdd(&lh[bin], 1u);              // LDS atomic: cheap
    }
  }
  reinterpret_cast<float4*>(wscores)[n] = make_float4(sc[0], sc[1], sc[2], sc[3]);

  __syncthreads();
  for (int i = threadIdx.x; i < NBP; i += 256)    // coalesced flush
    bhist[(size_t)blockIdx.x * NBP + i] = lh[i];

  red[threadIdx.x] = bmax;
  __syncthreads();
#pragma unroll
  for (int off = 128; off > 0; off >>= 1) {
    if (threadIdx.x < off) red[threadIdx.x] = fmaxf(red[threadIdx.x], red[threadIdx.x + off]);
    __syncthreads();
  }
  if (threadIdx.x == 0) wblockmax[blockIdx.x] = red[0];
}

// ---------------------------------------------------------------------------
// Kernel 2 (8 blocks x 512): COALESCED aggregation of the image's 64 block-
// hists (147 KB contiguous, stride-512 reads + LDS-atomic accumulate), then
// one-wave suffix scan -> exact X, C, rem. Also zeroes selcnt.
// ---------------------------------------------------------------------------
__global__ __launch_bounds__(512) void thresh_kernel(
    const u32* __restrict__ bhist, u32* __restrict__ Xthr, int* __restrict__ Carr,
    int* __restrict__ remv, int* __restrict__ selcnt)
{
  const int b = blockIdx.x, t = threadIdx.x;
  __shared__ u32 agg[NBP];
  __shared__ u32 X_s;
  __shared__ int C_sh, rem_sh;

  for (int i = t; i < NBP; i += 512) agg[i] = 0u;
  __syncthreads();

  const u32* src = bhist + (size_t)(b * 64) * NBP;   // contiguous 64*NBP words
  for (int idx = t; idx < 64 * NBP; idx += 512) {    // coalesced
    const u32 v = src[idx];
    if (v) atomicAdd(&agg[idx % NBP], v);            // LDS atomic
  }
  __syncthreads();

  if (t < 64) {
    const int lo = NBP - t * 9 - 9;      // lane 0 owns the TOP 9 bins
    u32 hb[9]; int mysum = 0;
#pragma unroll
    for (int q = 0; q < 9; ++q) { hb[q] = agg[lo + q]; mysum += (int)hb[q]; }
    int inc = mysum;                      // suffix-from-top inclusive scan
#pragma unroll
    for (int off = 1; off < 64; off <<= 1) {
      const int v = __shfl_up(inc, off);
      if (t >= off) inc += v;
    }
    const int tot = __shfl(inc, 63);
    const int pre = inc - mysum;
    if (tot < TSEL) {
      if (t == 63) { X_s = BASE16 << 16; C_sh = tot; rem_sh = 0; }
    } else if (pre < TSEL && inc >= TSEL) {  // unique boundary lane
      int cum = pre, kb = lo, qsel = 8;
      for (int q = 8; q >= 0; --q) {         // top bin of lane-chunk first
        cum += (int)hb[q];
        if (cum >= TSEL) { kb = lo + q; qsel = q; break; }
      }
      int C = cum;
      u32 Xbin;
      if (C > CAP) { C -= (int)hb[qsel]; Xbin = (u32)(kb + 1); }  // exclude tie-bin
      else Xbin = (u32)kb;
      X_s = (BASE16 + Xbin) << 16;
      C_sh = C; rem_sh = tot - C;
    }
  }
  __syncthreads();
  if (t == 0) { Xthr[b] = X_s; Carr[b] = C_sh; remv[b] = rem_sh; selcnt[b] = 0; }
}

// ---------------------------------------------------------------------------
// Kernel 3 (wide, 512 blocks): append keys >= X. Global atomicAdd on selcnt
// fires only ~C (<=256) times per image — negligible contention.
// ---------------------------------------------------------------------------
__global__ __launch_bounds__(256) void compact_kernel(
    const float* __restrict__ wscores, const u32* __restrict__ Xthr,
    int* __restrict__ selcnt, u64* __restrict__ keybuf)
{
  const int n = blockIdx.x * 256 + threadIdx.x;
  const int b = n >> 14;
  const u32 X = Xthr[b];
  const float4 v = reinterpret_cast<const float4*>(wscores)[n];
  const float ss[4] = {v.x, v.y, v.z, v.w};
  const int j0 = (n & (P_ - 1)) * 4;
#pragma unroll
  for (int c = 0; c < 4; ++c) {
    if (ss[c] > SCORE_T) {
      const u32 bb = __float_as_uint(ss[c]);
      if (bb >= X) {
        const int pos = atomicAdd(&selcnt[b], 1);
        if (pos < CAP) keybuf[b * CAP + pos] = ((u64)bb << 16) | (u64)(65535 - (j0 + c));
      }
    }
  }
}

// ---------------------------------------------------------------------------
// Kernel 4 (8 blocks x 512): O(CAP) — rank sort, candidate re-decode (bit-
// identical), pairwise masks, parallel greedy fixpoint, gather (+ slow path).
// ---------------------------------------------------------------------------
__global__ __launch_bounds__(512) void nms_kernel(
    const float* __restrict__ boxreg, const float* __restrict__ props,
    const int* __restrict__ image_hw,
    const float* __restrict__ wscores, const float* __restrict__ wblockmax,
    const u32* __restrict__ Xthr, const int* __restrict__ remv,
    const int* __restrict__ Carr, const u64* __restrict__ keybuf,
    const float* __restrict__ handside, const float* __restrict__ dxdymag,
    const float* __restrict__ contact, float* __restrict__ out)
{
  const int b = blockIdx.x, t = threadIdx.x;
  const float4* sc4 = reinterpret_cast<const float4*>(wscores) + (size_t)b * (M_ / 4);
  const u32 X = Xthr[b];
  const float Hf = (float)image_hw[0];
  const float Wf = (float)image_hw[1];

  __shared__ float maxv_s;
  __shared__ u64   kall[CAP];
  __shared__ u64   skey[CAP];
  __shared__ float4 cb4[CAP + K_];     // offset coords, swizzled slots
  __shared__ float4 cbx[CAP + K_];     // unshifted boxes (for output)
  __shared__ float carea[CAP + K_];
  __shared__ float cscf[CAP + K_];
  __shared__ int   cj[CAP + K_];
  __shared__ u64   supmask[CAP * 4];
  __shared__ u64   km[4];
  __shared__ int   chg;
  __shared__ int   kidx[K_];
  __shared__ int   kcount_s, nslow_s;
  __shared__ u64   red2[512];
  __shared__ u64   bitmap[1024];

  if (t < 64) {                        // per-image max coord from block maxima
    float v = wblockmax[b * 64 + t];
#pragma unroll
    for (int off = 32; off > 0; off >>= 1) v = fmaxf(v, __shfl_xor(v, off));
    if (t == 0) maxv_s = v;
  }
  if (t == 0) { kcount_s = 0; nslow_s = 0; }
  const int C = min(Carr[b], CAP);
  if (t < CAP) kall[t] = (t < C) ? keybuf[b * CAP + t] : 0ull;
  __syncthreads();
  const float maxv1 = maxv_s + 1.0f;   // (boxes.max() + 1.0)

  // ---- rank-by-counting sort (unique keys, descending) ----
  if (t < CAP) {
    const u64 my = kall[t];
    u32 r = 0;
    for (int u = 0; u < CAP; ++u) r += (kall[u] > my) ? 1u : 0u;
    if (t < C) skey[r] = my;
  }
  __syncthreads();

  // ---- candidate setup: re-decode (bit-identical to reference op order) ----
  if (t < C) {
    const u64 key = skey[t];
    const int j = 65535 - (int)(key & 0xFFFFull);
    const int cls = (j & 3) + 1;
    const int n = b * P_ + (j >> 2);
    const float4 rel = reinterpret_cast<const float4*>(boxreg)[n * 5 + cls];
    const float4 pr  = reinterpret_cast<const float4*>(props)[n];
    const float4 bx = decode_clip(rel, pr, Wf, Hf);
    const float offv = (float)cls * maxv1;
    const float ox1 = bx.x + offv, oy1 = bx.y + offv;
    const float ox2 = bx.z + offv, oy2 = bx.w + offv;
    const int ph = aphys(t);
    cb4[ph] = make_float4(ox1, oy1, ox2, oy2);
    cbx[ph] = bx;
    carea[ph] = (ox2 - ox1) * (oy2 - oy1);
    cscf[ph] = __uint_as_float((u32)(key >> 16));
    cj[ph] = j;
  }
  __syncthreads();

  // ---- pairwise suppression rows (self excluded) ----
  for (int task = t; task < C * 4; task += 512) {
    const int i = task >> 2, wq = task & 3;
    const float4 ib = cb4[aphys(i)];
    const float ia = carea[aphys(i)];
    u64 m = 0;
    const int qb = wq * 64, qe = min(qb + 64, C);
    for (int q = qb; q < qe; ++q) {
      if (q == i) continue;
      const int qp = aphys(q);
      const float4 qbx = cb4[qp];
      const float ltx = fmaxf(ib.x, qbx.x);
      const float lty = fmaxf(ib.y, qbx.y);
      const float rbx = fminf(ib.z, qbx.z);
      const float rby = fminf(ib.w, qbx.w);
      const float iw = fmaxf(rbx - ltx, 0.f);
      const float ih = fmaxf(rby - lty, 0.f);
      const float inter = iw * ih;
      const float iou = inter / (ia + carea[qp] - inter);  // a1+a2-inter
      if (iou > 0.5f) m |= 1ull << (q - qb);               // NaN -> false (ref)
    }
    supmask[i * 4 + wq] = m;
  }
  __syncthreads();

  // ---- parallel greedy fixpoint (unique fixpoint == greedy) ----
  const int wi = t >> 6, bi = t & 63;
  const u64 lowmask = bi ? (~0ull >> (64 - bi)) : 0ull;
  u64 rb0 = 0, rb1 = 0, rb2 = 0, rb3 = 0;
  const bool alive = (t < C);
  if (t < CAP) {
    rb0 = supmask[t * 4 + 0];
    rb1 = supmask[t * 4 + 1];
    rb2 = supmask[t * 4 + 2];
    rb3 = supmask[t * 4 + 3];
    const u64 m0 = (wi > 0) ? ~0ull : lowmask;
    const u64 m1 = (wi > 1) ? ~0ull : ((wi == 1) ? lowmask : 0ull);
    const u64 m2 = (wi > 2) ? ~0ull : ((wi == 2) ? lowmask : 0ull);
    const u64 m3 = (wi == 3) ? lowmask : 0ull;
    rb0 &= m0; rb1 &= m1; rb2 &= m2; rb3 &= m3;   // suppressors j < i only
    const u64 bal = __ballot(alive ? 1 : 0);
    if (bi == 0) km[wi] = bal;
  }
  __syncthreads();
  while (true) {
    if (t == 0) chg = 0;
    __syncthreads();
    u64 nb = 0;
    if (t < CAP) {
      const u64 k0 = km[0], k1 = km[1], k2 = km[2], k3 = km[3];
      const bool sup = ((rb0 & k0) | (rb1 & k1) | (rb2 & k2) | (rb3 & k3)) != 0ull;
      const bool kn = alive && !sup;
      nb = __ballot(kn ? 1 : 0);
      if (bi == 0 && nb != km[wi]) chg = 1;
    }
    __syncthreads();
    if (t < CAP && bi == 0) km[wi] = nb;
    __syncthreads();
    if (!chg) break;
  }

  // ---- extract keeps in index order (== greedy pop order) ----
  if (t < CAP) {
    const u64 kw = km[wi];
    if ((kw >> bi) & 1ull) {
      int pb = 0;
      if (wi > 0) pb += __popcll(km[0]);
      if (wi > 1) pb += __popcll(km[1]);
      if (wi > 2) pb += __popcll(km[2]);
      pb += __popcll(kw & lowmask);
      if (pb < K_) kidx[pb] = t;
    }
    if (t == 0) {
      kcount_s = min(__popcll(km[0]) + __popcll(km[1]) +
                     __popcll(km[2]) + __popcll(km[3]), K_);
    }
  }
  __syncthreads();

  // ---- slow-path continuation (exactness; skipped on benign data) ----
  if (kcount_s < K_ && remv[b] > 0) {
    for (int i = t; i < 1024; i += 512) bitmap[i] = 0ull;
    __syncthreads();
    while (true) {
      u64 best = 0ull;
      for (int i = t; i < M_ / 4; i += 512) {
        const float4 v = sc4[i];
        const float ss[4] = {v.x, v.y, v.z, v.w};
#pragma unroll
        for (int c = 0; c < 4; ++c) {
          if (ss[c] > SCORE_T) {
            const u32 bb = __float_as_uint(ss[c]);
            if (bb < X) {
              const int j = i * 4 + c;
              if (!((bitmap[j >> 6] >> (j & 63)) & 1ull)) {
                const u64 key = ((u64)bb << 16) | (u64)(65535 - j);
                if (key > best) best = key;
              }
            }
          }
        }
      }
      red2[t] = best;
      __syncthreads();
      for (int off = 256; off > 0; off >>= 1) {
        if (t < off && red2[t + off] > red2[t]) red2[t] = red2[t + off];
        __syncthreads();
      }
      const u64 wkey = red2[0];
      if (wkey == 0ull) break;
      if (t == 0) {
        const int j = 65535 - (int)(wkey & 0xFFFFull);
        bitmap[j >> 6] |= 1ull << (j & 63);
        const int cls = (j & 3) + 1;
        const int n = b * P_ + (j >> 2);
        const float4 rel = reinterpret_cast<const float4*>(boxreg)[n * 5 + cls];
        const float4 pr  = reinterpret_cast<const float4*>(props)[n];
        const float4 bx = decode_clip(rel, pr, Wf, Hf);
        const float offv = (float)cls * maxv1;
        const float ox1 = bx.x + offv, oy1 = bx.y + offv;
        const float ox2 = bx.z + offv, oy2 = bx.w + offv;
        const float ar = (ox2 - ox1) * (oy2 - oy1);
        bool sup = false;
        for (int k2 = 0; k2 < kcount_s; ++k2) {
          const int ki = aphys(kidx[k2]);
          const float4 kb = cb4[ki];
          const float ltx = fmaxf(kb.x, ox1);
          const float lty = fmaxf(kb.y, oy1);
          const float rbx = fminf(kb.z, ox2);
          const float rby = fminf(kb.w, oy2);
          const float iw = fmaxf(rbx - ltx, 0.f);
          const float ih = fmaxf(rby - lty, 0.f);
          const float inter = iw * ih;
          const float iou = inter / (carea[ki] + ar - inter);
          if (iou > 0.5f) { sup = true; break; }
        }
        if (!sup) {
          const int slot = CAP + nslow_s;        // aphys(slot) == slot
          cb4[slot] = make_float4(ox1, oy1, ox2, oy2);
          cbx[slot] = bx;
          carea[slot] = ar;
          cscf[slot] = __uint_as_float((u32)(wkey >> 16));
          cj[slot] = j;
          kidx[kcount_s] = slot;
          ++nslow_s;
          ++kcount_s;
        }
      }
      __syncthreads();
      if (kcount_s >= K_) break;
    }
    __syncthreads();
  }
  __syncthreads();

  // ---- gather outputs ----
  const int kc = kcount_s;
  if (t < K_) {
    const int r = t;
    float ob0 = 0.f, ob1 = 0.f, ob2 = 0.f, ob3 = 0.f;
    float osc = 0.f, olab = 0.f, oside = 0.f;
    float od0 = 0.f, od1 = 0.f, od2 = 0.f;
    float ocon = 0.f, okeep = 0.f;
    if (r < kc) {
      const int idx = kidx[r];
      const int ph = aphys(idx);
      const int j = cj[ph];
      const int cls = (j & 3) + 1;
      const int n = b * P_ + (j >> 2);
      const float4 bx = cbx[ph];                    // unshifted output box
      ob0 = bx.x; ob1 = bx.y; ob2 = bx.z; ob3 = bx.w;
      osc = cscf[ph];
      olab = (float)cls;
      oside = (handside[n * 5 + cls] > 0.f) ? 1.f : 0.f;  // sigmoid>0.5 <=> x>0
      od0 = dxdymag[n * 15 + cls * 3 + 0];
      od1 = dxdymag[n * 15 + cls * 3 + 1];
      od2 = dxdymag[n * 15 + cls * 3 + 2];
      float bvv = contact[n * 25 + cls * 5 + 0];
      int best = 0;
#pragma unroll
      for (int i = 1; i < 5; ++i) {
        const float ci = contact[n * 25 + cls * 5 + i];
        if (ci > bvv) { bvv = ci; best = i; }
      }
      ocon = (float)best;
      okeep = 1.f;
    }
    const int gb = b * K_ + r;
    out[gb * 4 + 0] = ob0;
    out[gb * 4 + 1] = ob1;
    out[gb * 4 + 2] = ob2;
    out[gb * 4 + 3] = ob3;
    out[3200 + gb] = osc;
    out[4000 + gb] = olab;
    out[4800 + gb] = oside;
    out[5600 + gb * 3 + 0] = od0;
    out[5600 + gb * 3 + 1] = od1;
    out[5600 + gb * 3 + 2] = od2;
    out[8000 + gb] = ocon;
    out[8800 + gb] = okeep;
  }
}

// ---------------------------------------------------------------------------
extern "C" void kernel_launch(void* const* d_in, const int* in_sizes, int n_in,
                              void* d_out, int out_size, void* d_ws, size_t ws_size,
                              hipStream_t stream) {
  const float* class_logits = (const float*)d_in[0];
  const float* box_reg      = (const float*)d_in[1];
  const float* handside     = (const float*)d_in[2];
  const float* dxdymag      = (const float*)d_in[3];
  const float* contact      = (const float*)d_in[4];
  const float* proposals    = (const float*)d_in[5];
  const int*   image_hw     = (const int*)d_in[6];
  float* out = (float*)d_out;

  char* ws = (char*)d_ws;
  u32*   bhist     = (u32*)  ws;                       // 512*576*4 = 1179648 B
  u32*   Xthr      = (u32*)  (ws + 1179648);           // 32 B
  int*   Carr      = (int*)  (ws + 1179680);           // 32 B
  int*   remv      = (int*)  (ws + 1179712);           // 32 B
  int*   selcnt    = (int*)  (ws + 1179744);           // 32 B
  float* wblockmax = (float*)(ws + 1181824);           // 2048 B
  u64*   keybuf    = (u64*)  (ws + 1183872);           // 16384 B
  float* wscores   = (float*)(ws + 2097152);           // 2 MiB (ends 4 MiB)

  prep_kernel<<<dim3(512), dim3(256), 0, stream>>>(
      class_logits, box_reg, proposals, image_hw, wscores, wblockmax, bhist);
  thresh_kernel<<<dim3(B_), dim3(512), 0, stream>>>(
      bhist, Xthr, Carr, remv, selcnt);
  compact_kernel<<<dim3(512), dim3(256), 0, stream>>>(
      wscores, Xthr, selcnt, keybuf);
  nms_kernel<<<dim3(B_), dim3(512), 0, stream>>>(
      box_reg, proposals, image_hw, wscores, wblockmax, Xthr, remv, Carr,
      keybuf, handside, dxdymag, contact, out);
}

// Round 11
// 57.498 us; speedup vs baseline: 1.4966x; 1.4966x over previous
//
#include <hip/hip_runtime.h>
#include <cstdint>

typedef unsigned int u32;
typedef unsigned long long u64;

constexpr int B_ = 8;
constexpr int P_ = 16384;
constexpr int K_ = 100;
constexpr int M_ = P_ * 4;            // candidates per image, j = p*4+(cls-1)
constexpr int TSEL = 192;             // selection target
constexpr int CAP = 256;              // selection capacity (= one resolve chunk)
constexpr int NBP = 576;              // hist bins: (bits>>16) - BASE16
constexpr u32 BASE16 = 0x3D4Cu;       // bits(0.05f) >> 16
constexpr float SCORE_T = 0.05f;
constexpr float CLIPV = 4.135166556742356f;  // log(1000/16)

// swizzled candidate slot: rotate low-6 bits by 4*(group) -> the 4 simultaneous
// row-group reads in the pairwise phase hit 2 banks (2-way == free) not 4-way.
__device__ inline int aphys(int i) {
  return (i < CAP) ? ((((i & 63) + ((i >> 6) << 2)) & 63) | (i & 192)) : i;
}

// decode + clip, reference op order (bit-identical everywhere it's used)
__device__ inline float4 decode_clip(float4 rel, float4 pr, float Wf, float Hf) {
  const float w  = pr.z - pr.x;
  const float h  = pr.w - pr.y;
  const float cx = pr.x + 0.5f * w;
  const float cy = pr.y + 0.5f * h;
  const float dx = rel.x / 10.0f;
  const float dy = rel.y / 10.0f;
  const float dw = fminf(rel.z / 5.0f, CLIPV);
  const float dh = fminf(rel.w / 5.0f, CLIPV);
  const float pcx = dx * w + cx;
  const float pcy = dy * h + cy;
  const float pw = expf(dw) * w;
  const float ph = expf(dh) * h;
  float x1 = pcx - 0.5f * pw, y1 = pcy - 0.5f * ph;
  float x2 = pcx + 0.5f * pw, y2 = pcy + 0.5f * ph;
  x1 = fminf(fmaxf(x1, 0.f), Wf);
  x2 = fminf(fmaxf(x2, 0.f), Wf);
  y1 = fminf(fmaxf(y1, 0.f), Hf);
  y2 = fminf(fmaxf(y2, 0.f), Hf);
  return make_float4(x1, y1, x2, y2);
}

// ---------------------------------------------------------------------------
// Kernel 1 (wide, 512 blocks, image-pure): softmax + decode (for max coord;
// boxes NOT stored) + scores store + per-block LDS hist -> plain flush.
// NO global atomics anywhere (cross-XCD line-migration cost ~30+ us, R10).
// ---------------------------------------------------------------------------
__global__ __launch_bounds__(256) void prep_kernel(
    const float* __restrict__ logits,     // [N,5]
    const float* __restrict__ boxreg,     // [N,20]
    const float* __restrict__ props,      // [N,4]
    const int*  __restrict__ image_hw,    // {H,W}
    float* __restrict__ wscores,          // [B*M]
    float* __restrict__ wblockmax,        // [512]
    u32*   __restrict__ bhist)            // [512][NBP]
{
  __shared__ u32 lh[NBP];
  __shared__ float red[256];
  for (int i = threadIdx.x; i < NBP; i += 256) lh[i] = 0u;
  __syncthreads();

  const int n = blockIdx.x * 256 + threadIdx.x;   // 512*256 == B*P

  float l[5];
#pragma unroll
  for (int i = 0; i < 5; ++i) l[i] = logits[n * 5 + i];
  float mx = l[0];
#pragma unroll
  for (int i = 1; i < 5; ++i) mx = fmaxf(mx, l[i]);
  float e[5]; float ssum = 0.f;
#pragma unroll
  for (int i = 0; i < 5; ++i) { e[i] = expf(l[i] - mx); ssum += e[i]; }

  const float4 pr = reinterpret_cast<const float4*>(props)[n];
  const float Hf = (float)image_hw[0];
  const float Wf = (float)image_hw[1];

  float bmax = 0.f;
  float sc[4];
#pragma unroll
  for (int c = 1; c < 5; ++c) {
    const float4 rel = reinterpret_cast<const float4*>(boxreg)[n * 5 + c];
    const float4 bx = decode_clip(rel, pr, Wf, Hf);
    bmax = fmaxf(bmax, fmaxf(fmaxf(bx.x, bx.z), fmaxf(bx.y, bx.w)));
    const float sv = e[c] / ssum;
    sc[c - 1] = sv;
    if (sv > SCORE_T) {
      u32 bin = (__float_as_uint(sv) >> 16) - BASE16;
      if (bin >= (u32)NBP) bin = NBP - 1;
      atomicAdd(&lh[bin], 1u);              // LDS atomic: cheap
    }
  }
  reinterpret_cast<float4*>(wscores)[n] = make_float4(sc[0], sc[1], sc[2], sc[3]);

  __syncthreads();
  for (int i = threadIdx.x; i < NBP; i += 256)    // coalesced flush
    bhist[(size_t)blockIdx.x * NBP + i] = lh[i];

  red[threadIdx.x] = bmax;
  __syncthreads();
#pragma unroll
  for (int off = 128; off > 0; off >>= 1) {
    if (threadIdx.x < off) red[threadIdx.x] = fmaxf(red[threadIdx.x], red[threadIdx.x + off]);
    __syncthreads();
  }
  if (threadIdx.x == 0) wblockmax[blockIdx.x] = red[0];
}

// ---------------------------------------------------------------------------
// Kernel 2 (8 blocks x 1024): everything per-image in ONE kernel, no global
// atomics, no intermediate global buffers beyond prep's outputs.
//   phase 0: coalesced bhist aggregation -> exact threshold X, C, rem
//   phase 1: coalesced score-slice scan -> keys >= X into LDS
//   phase 2: rank sort + re-decode + pairwise masks + greedy fixpoint + gather
// ---------------------------------------------------------------------------
__global__ __launch_bounds__(1024) void nms_kernel(
    const float* __restrict__ boxreg, const float* __restrict__ props,
    const int* __restrict__ image_hw,
    const float* __restrict__ wscores, const float* __restrict__ wblockmax,
    const u32* __restrict__ bhist,
    const float* __restrict__ handside, const float* __restrict__ dxdymag,
    const float* __restrict__ contact, float* __restrict__ out)
{
  const int b = blockIdx.x, t = threadIdx.x;
  const float4* sc4 = reinterpret_cast<const float4*>(wscores) + (size_t)b * (M_ / 4);
  const float Hf = (float)image_hw[0];
  const float Wf = (float)image_hw[1];

  __shared__ u32   agg[NBP];
  __shared__ float maxv_s;
  __shared__ u32   X_s;
  __shared__ int   C_sh, rem_sh, cnt_s;
  __shared__ u64   kall[CAP];
  __shared__ u64   skey[CAP];
  __shared__ float4 cb4[CAP + K_];     // offset coords, swizzled slots
  __shared__ float4 cbx[CAP + K_];     // unshifted boxes (for output)
  __shared__ float carea[CAP + K_];
  __shared__ float cscf[CAP + K_];
  __shared__ int   cj[CAP + K_];
  __shared__ u64   supmask[CAP * 4];
  __shared__ u64   km[4];
  __shared__ int   chg;
  __shared__ int   kidx[K_];
  __shared__ int   kcount_s, nslow_s;
  __shared__ u64   red2[1024];
  __shared__ u64   bitmap[1024];

  // ---- phase 0a: init + per-image max coord ----
  for (int i = t; i < NBP; i += 1024) agg[i] = 0u;
  if (t < CAP) kall[t] = 0ull;
  if (t == 0) { kcount_s = 0; nslow_s = 0; cnt_s = 0; }
  if (t >= 64 && t < 128) {
    float v = wblockmax[b * 64 + (t - 64)];
#pragma unroll
    for (int off = 32; off > 0; off >>= 1) v = fmaxf(v, __shfl_xor(v, off));
    if (t == 64) maxv_s = v;
  }
  __syncthreads();

  // ---- phase 0b: coalesced aggregation of this image's 64 block-hists ----
  {
    const u32* src = bhist + (size_t)(b * 64) * NBP;   // contiguous 64*NBP words
    for (int idx = t; idx < 64 * NBP; idx += 1024) {   // consecutive lanes ->
      const u32 v = src[idx];                          // consecutive bins: no
      if (v) atomicAdd(&agg[idx % NBP], v);            // LDS bank conflicts
    }
  }
  __syncthreads();

  // ---- phase 0c: one-wave suffix scan -> exact X, C, rem ----
  if (t < 64) {
    const int lo = NBP - t * 9 - 9;      // lane 0 owns the TOP 9 bins
    u32 hb[9]; int mysum = 0;
#pragma unroll
    for (int q = 0; q < 9; ++q) { hb[q] = agg[lo + q]; mysum += (int)hb[q]; }
    int inc = mysum;                      // suffix-from-top inclusive scan
#pragma unroll
    for (int off = 1; off < 64; off <<= 1) {
      const int v = __shfl_up(inc, off);
      if (t >= off) inc += v;
    }
    const int tot = __shfl(inc, 63);
    const int pre = inc - mysum;
    if (tot < TSEL) {
      if (t == 63) { X_s = BASE16 << 16; C_sh = tot; rem_sh = 0; }
    } else if (pre < TSEL && inc >= TSEL) {  // unique boundary lane
      int cum = pre, kb = lo, qsel = 8;
      for (int q = 8; q >= 0; --q) {         // top bin of lane-chunk first
        cum += (int)hb[q];
        if (cum >= TSEL) { kb = lo + q; qsel = q; break; }
      }
      int C = cum;
      u32 Xbin;
      if (C > CAP) { C -= (int)hb[qsel]; Xbin = (u32)(kb + 1); }  // exclude tie-bin
      else Xbin = (u32)kb;
      X_s = (BASE16 + Xbin) << 16;
      C_sh = C; rem_sh = tot - C;
    }
  }
  __syncthreads();
  const u32 X = X_s;
  const float maxv1 = maxv_s + 1.0f;   // (boxes.max() + 1.0)

  // ---- phase 1: coalesced score scan, collect keys >= X into LDS ----
  for (int i = t; i < M_ / 4; i += 1024) {
    const float4 v = sc4[i];
    const float ss[4] = {v.x, v.y, v.z, v.w};
    const int j0 = i * 4;
#pragma unroll
    for (int c = 0; c < 4; ++c) {
      if (ss[c] > SCORE_T) {
        const u32 bb = __float_as_uint(ss[c]);
        if (bb >= X) {
          const int pos = atomicAdd(&cnt_s, 1);        // LDS atomic
          if (pos < CAP) kall[pos] = ((u64)bb << 16) | (u64)(65535 - (j0 + c));
        }
      }
    }
  }
  __syncthreads();
  const int C = min(C_sh, CAP);

  // ---- phase 2a: rank-by-counting sort (unique keys, descending) ----
  if (t < CAP) {
    const u64 my = kall[t];
    u32 r = 0;
    for (int u = 0; u < CAP; ++u) r += (kall[u] > my) ? 1u : 0u;
    if (t < C) skey[r] = my;
  }
  __syncthreads();

  // ---- phase 2b: candidate re-decode (bit-identical to reference) ----
  if (t < C) {
    const u64 key = skey[t];
    const int j = 65535 - (int)(key & 0xFFFFull);
    const int cls = (j & 3) + 1;
    const int n = b * P_ + (j >> 2);
    const float4 rel = reinterpret_cast<const float4*>(boxreg)[n * 5 + cls];
    const float4 pr  = reinterpret_cast<const float4*>(props)[n];
    const float4 bx = decode_clip(rel, pr, Wf, Hf);
    const float offv = (float)cls * maxv1;
    const float ox1 = bx.x + offv, oy1 = bx.y + offv;
    const float ox2 = bx.z + offv, oy2 = bx.w + offv;
    const int ph = aphys(t);
    cb4[ph] = make_float4(ox1, oy1, ox2, oy2);
    cbx[ph] = bx;
    carea[ph] = (ox2 - ox1) * (oy2 - oy1);
    cscf[ph] = __uint_as_float((u32)(key >> 16));
    cj[ph] = j;
  }
  __syncthreads();

  // ---- phase 2c: pairwise suppression rows (self excluded) ----
  for (int task = t; task < C * 4; task += 1024) {
    const int i = task >> 2, wq = task & 3;
    const float4 ib = cb4[aphys(i)];
    const float ia = carea[aphys(i)];
    u64 m = 0;
    const int qb = wq * 64, qe = min(qb + 64, C);
    for (int q = qb; q < qe; ++q) {
      if (q == i) continue;
      const int qp = aphys(q);
      const float4 qbx = cb4[qp];
      const float ltx = fmaxf(ib.x, qbx.x);
      const float lty = fmaxf(ib.y, qbx.y);
      const float rbx = fminf(ib.z, qbx.z);
      const float rby = fminf(ib.w, qbx.w);
      const float iw = fmaxf(rbx - ltx, 0.f);
      const float ih = fmaxf(rby - lty, 0.f);
      const float inter = iw * ih;
      const float iou = inter / (ia + carea[qp] - inter);  // a1+a2-inter
      if (iou > 0.5f) m |= 1ull << (q - qb);               // NaN -> false (ref)
    }
    supmask[i * 4 + wq] = m;
  }
  __syncthreads();

  // ---- phase 2d: parallel greedy fixpoint (unique fixpoint == greedy) ----
  const int wi = t >> 6, bi = t & 63;
  const u64 lowmask = bi ? (~0ull >> (64 - bi)) : 0ull;
  u64 rb0 = 0, rb1 = 0, rb2 = 0, rb3 = 0;
  const bool alive = (t < C);
  if (t < CAP) {
    rb0 = supmask[t * 4 + 0];
    rb1 = supmask[t * 4 + 1];
    rb2 = supmask[t * 4 + 2];
    rb3 = supmask[t * 4 + 3];
    const u64 m0 = (wi > 0) ? ~0ull : lowmask;
    const u64 m1 = (wi > 1) ? ~0ull : ((wi == 1) ? lowmask : 0ull);
    const u64 m2 = (wi > 2) ? ~0ull : ((wi == 2) ? lowmask : 0ull);
    const u64 m3 = (wi == 3) ? lowmask : 0ull;
    rb0 &= m0; rb1 &= m1; rb2 &= m2; rb3 &= m3;   // suppressors j < i only
    const u64 bal = __ballot(alive ? 1 : 0);
    if (bi == 0) km[wi] = bal;
  }
  __syncthreads();
  while (true) {
    if (t == 0) chg = 0;
    __syncthreads();
    u64 nb = 0;
    if (t < CAP) {
      const u64 k0 = km[0], k1 = km[1], k2 = km[2], k3 = km[3];
      const bool sup = ((rb0 & k0) | (rb1 & k1) | (rb2 & k2) | (rb3 & k3)) != 0ull;
      const bool kn = alive && !sup;
      nb = __ballot(kn ? 1 : 0);
      if (bi == 0 && nb != km[wi]) chg = 1;
    }
    __syncthreads();
    if (t < CAP && bi == 0) km[wi] = nb;
    __syncthreads();
    if (!chg) break;
  }

  // ---- phase 2e: extract keeps in index order (== greedy pop order) ----
  if (t < CAP) {
    const u64 kw = km[wi];
    if ((kw >> bi) & 1ull) {
      int pb = 0;
      if (wi > 0) pb += __popcll(km[0]);
      if (wi > 1) pb += __popcll(km[1]);
      if (wi > 2) pb += __popcll(km[2]);
      pb += __popcll(kw & lowmask);
      if (pb < K_) kidx[pb] = t;
    }
    if (t == 0) {
      kcount_s = min(__popcll(km[0]) + __popcll(km[1]) +
                     __popcll(km[2]) + __popcll(km[3]), K_);
    }
  }
  __syncthreads();

  // ---- slow-path continuation (exactness; skipped on benign data) ----
  if (kcount_s < K_ && rem_sh > 0) {
    bitmap[t] = 0ull;
    __syncthreads();
    while (true) {
      u64 best = 0ull;
      for (int i = t; i < M_ / 4; i += 1024) {
        const float4 v = sc4[i];
        const float ss[4] = {v.x, v.y, v.z, v.w};
#pragma unroll
        for (int c = 0; c < 4; ++c) {
          if (ss[c] > SCORE_T) {
            const u32 bb = __float_as_uint(ss[c]);
            if (bb < X) {
              const int j = i * 4 + c;
              if (!((bitmap[j >> 6] >> (j & 63)) & 1ull)) {
                const u64 key = ((u64)bb << 16) | (u64)(65535 - j);
                if (key > best) best = key;
              }
            }
          }
        }
      }
      red2[t] = best;
      __syncthreads();
      for (int off = 512; off > 0; off >>= 1) {
        if (t < off && red2[t + off] > red2[t]) red2[t] = red2[t + off];
        __syncthreads();
      }
      const u64 wkey = red2[0];
      if (wkey == 0ull) break;
      if (t == 0) {
        const int j = 65535 - (int)(wkey & 0xFFFFull);
        bitmap[j >> 6] |= 1ull << (j & 63);
        const int cls = (j & 3) + 1;
        const int n = b * P_ + (j >> 2);
        const float4 rel = reinterpret_cast<const float4*>(boxreg)[n * 5 + cls];
        const float4 pr  = reinterpret_cast<const float4*>(props)[n];
        const float4 bx = decode_clip(rel, pr, Wf, Hf);
        const float offv = (float)cls * maxv1;
        const float ox1 = bx.x + offv, oy1 = bx.y + offv;
        const float ox2 = bx.z + offv, oy2 = bx.w + offv;
        const float ar = (ox2 - ox1) * (oy2 - oy1);
        bool sup = false;
        for (int k2 = 0; k2 < kcount_s; ++k2) {
          const int ki = aphys(kidx[k2]);
          const float4 kb = cb4[ki];
          const float ltx = fmaxf(kb.x, ox1);
          const float lty = fmaxf(kb.y, oy1);
          const float rbx = fminf(kb.z, ox2);
          const float rby = fminf(kb.w, oy2);
          const float iw = fmaxf(rbx - ltx, 0.f);
          const float ih = fmaxf(rby - lty, 0.f);
          const float inter = iw * ih;
          const float iou = inter / (carea[ki] + ar - inter);
          if (iou > 0.5f) { sup = true; break; }
        }
        if (!sup) {
          const int slot = CAP + nslow_s;        // aphys(slot) == slot
          cb4[slot] = make_float4(ox1, oy1, ox2, oy2);
          cbx[slot] = bx;
          carea[slot] = ar;
          cscf[slot] = __uint_as_float((u32)(wkey >> 16));
          cj[slot] = j;
          kidx[kcount_s] = slot;
          ++nslow_s;
          ++kcount_s;
        }
      }
      __syncthreads();
      if (kcount_s >= K_) break;
    }
    __syncthreads();
  }
  __syncthreads();

  // ---- gather outputs ----
  const int kc = kcount_s;
  if (t < K_) {
    const int r = t;
    float ob0 = 0.f, ob1 = 0.f, ob2 = 0.f, ob3 = 0.f;
    float osc = 0.f, olab = 0.f, oside = 0.f;
    float od0 = 0.f, od1 = 0.f, od2 = 0.f;
    float ocon = 0.f, okeep = 0.f;
    if (r < kc) {
      const int idx = kidx[r];
      const int ph = aphys(idx);
      const int j = cj[ph];
      const int cls = (j & 3) + 1;
      const int n = b * P_ + (j >> 2);
      const float4 bx = cbx[ph];                    // unshifted output box
      ob0 = bx.x; ob1 = bx.y; ob2 = bx.z; ob3 = bx.w;
      osc = cscf[ph];
      olab = (float)cls;
      oside = (handside[n * 5 + cls] > 0.f) ? 1.f : 0.f;  // sigmoid>0.5 <=> x>0
      od0 = dxdymag[n * 15 + cls * 3 + 0];
      od1 = dxdymag[n * 15 + cls * 3 + 1];
      od2 = dxdymag[n * 15 + cls * 3 + 2];
      float bvv = contact[n * 25 + cls * 5 + 0];
      int best = 0;
#pragma unroll
      for (int i = 1; i < 5; ++i) {
        const float ci = contact[n * 25 + cls * 5 + i];
        if (ci > bvv) { bvv = ci; best = i; }
      }
      ocon = (float)best;
      okeep = 1.f;
    }
    const int gb = b * K_ + r;
    out[gb * 4 + 0] = ob0;
    out[gb * 4 + 1] = ob1;
    out[gb * 4 + 2] = ob2;
    out[gb * 4 + 3] = ob3;
    out[3200 + gb] = osc;
    out[4000 + gb] = olab;
    out[4800 + gb] = oside;
    out[5600 + gb * 3 + 0] = od0;
    out[5600 + gb * 3 + 1] = od1;
    out[5600 + gb * 3 + 2] = od2;
    out[8000 + gb] = ocon;
    out[8800 + gb] = okeep;
  }
}

// ---------------------------------------------------------------------------
extern "C" void kernel_launch(void* const* d_in, const int* in_sizes, int n_in,
                              void* d_out, int out_size, void* d_ws, size_t ws_size,
                              hipStream_t stream) {
  const float* class_logits = (const float*)d_in[0];
  const float* box_reg      = (const float*)d_in[1];
  const float* handside     = (const float*)d_in[2];
  const float* dxdymag      = (const float*)d_in[3];
  const float* contact      = (const float*)d_in[4];
  const float* proposals    = (const float*)d_in[5];
  const int*   image_hw     = (const int*)d_in[6];
  float* out = (float*)d_out;

  char* ws = (char*)d_ws;
  u32*   bhist     = (u32*)  ws;                       // 512*576*4 = 1179648 B
  float* wblockmax = (float*)(ws + 1179648);           // 2048 B
  float* wscores   = (float*)(ws + 2097152);           // 2 MiB (ends 4 MiB)

  prep_kernel<<<dim3(512), dim3(256), 0, stream>>>(
      class_logits, box_reg, proposals, image_hw, wscores, wblockmax, bhist);
  nms_kernel<<<dim3(B_), dim3(1024), 0, stream>>>(
      box_reg, proposals, image_hw, wscores, wblockmax, bhist,
      handside, dxdymag, contact, out);
}

// Round 12
// 54.731 us; speedup vs baseline: 1.5723x; 1.0505x over previous
//
#include <hip/hip_runtime.h>
#include <cstdint>

typedef unsigned int u32;
typedef unsigned long long u64;

constexpr int B_ = 8;
constexpr int P_ = 16384;
constexpr int K_ = 100;
constexpr int M_ = P_ * 4;            // candidates per image, j = p*4+(cls-1)
constexpr int TSEL = 192;             // selection target
constexpr int CAP = 256;              // selection capacity (= one resolve chunk)
constexpr int NBP = 576;              // hist bins: (bits>>16) - BASE16
constexpr u32 BASE16 = 0x3D4Cu;       // bits(0.05f) >> 16
constexpr float SCORE_T = 0.05f;
constexpr float CLIPV = 4.135166556742356f;  // log(1000/16)

// Session rules (measured): NO device-scope atomics on small shared regions
// (R8/R10: ~30+us line-migration). NO runtime memset nodes (R7: 40us fill).
// Full-array passes must run WIDE (512 blocks); 8-block kernels do O(CAP) only.

// swizzled candidate slot: rotate low-6 bits by 4*(group) -> the 4 simultaneous
// row-group reads in the pairwise phase hit 2 banks (2-way == free) not 4-way.
__device__ inline int aphys(int i) {
  return (i < CAP) ? ((((i & 63) + ((i >> 6) << 2)) & 63) | (i & 192)) : i;
}

// decode + clip, reference op order (bit-identical everywhere it's used)
__device__ inline float4 decode_clip(float4 rel, float4 pr, float Wf, float Hf) {
  const float w  = pr.z - pr.x;
  const float h  = pr.w - pr.y;
  const float cx = pr.x + 0.5f * w;
  const float cy = pr.y + 0.5f * h;
  const float dx = rel.x / 10.0f;
  const float dy = rel.y / 10.0f;
  const float dw = fminf(rel.z / 5.0f, CLIPV);
  const float dh = fminf(rel.w / 5.0f, CLIPV);
  const float pcx = dx * w + cx;
  const float pcy = dy * h + cy;
  const float pw = expf(dw) * w;
  const float ph = expf(dh) * h;
  float x1 = pcx - 0.5f * pw, y1 = pcy - 0.5f * ph;
  float x2 = pcx + 0.5f * pw, y2 = pcy + 0.5f * ph;
  x1 = fminf(fmaxf(x1, 0.f), Wf);
  x2 = fminf(fmaxf(x2, 0.f), Wf);
  y1 = fminf(fmaxf(y1, 0.f), Hf);
  y2 = fminf(fmaxf(y2, 0.f), Hf);
  return make_float4(x1, y1, x2, y2);
}

// ---------------------------------------------------------------------------
// Kernel 1 (512 x 256, image-pure blocks): softmax + decode (max coord only)
// + scores store + per-block LDS hist flushed with plain coalesced stores.
// ---------------------------------------------------------------------------
__global__ __launch_bounds__(256) void prep_kernel(
    const float* __restrict__ logits, const float* __restrict__ boxreg,
    const float* __restrict__ props, const int* __restrict__ image_hw,
    float* __restrict__ wscores, float* __restrict__ wblockmax,
    u32* __restrict__ bhist)
{
  __shared__ u32 lh[NBP];
  __shared__ float red[256];
  for (int i = threadIdx.x; i < NBP; i += 256) lh[i] = 0u;
  __syncthreads();

  const int n = blockIdx.x * 256 + threadIdx.x;   // 512*256 == B*P

  float l[5];
#pragma unroll
  for (int i = 0; i < 5; ++i) l[i] = logits[n * 5 + i];
  float mx = l[0];
#pragma unroll
  for (int i = 1; i < 5; ++i) mx = fmaxf(mx, l[i]);
  float e[5]; float ssum = 0.f;
#pragma unroll
  for (int i = 0; i < 5; ++i) { e[i] = expf(l[i] - mx); ssum += e[i]; }

  const float4 pr = reinterpret_cast<const float4*>(props)[n];
  const float Hf = (float)image_hw[0];
  const float Wf = (float)image_hw[1];

  float bmax = 0.f;
  float sc[4];
#pragma unroll
  for (int c = 1; c < 5; ++c) {
    const float4 rel = reinterpret_cast<const float4*>(boxreg)[n * 5 + c];
    const float4 bx = decode_clip(rel, pr, Wf, Hf);
    bmax = fmaxf(bmax, fmaxf(fmaxf(bx.x, bx.z), fmaxf(bx.y, bx.w)));
    const float sv = e[c] / ssum;
    sc[c - 1] = sv;
    if (sv > SCORE_T) {
      u32 bin = (__float_as_uint(sv) >> 16) - BASE16;
      if (bin >= (u32)NBP) bin = NBP - 1;
      atomicAdd(&lh[bin], 1u);              // LDS atomic: cheap
    }
  }
  reinterpret_cast<float4*>(wscores)[n] = make_float4(sc[0], sc[1], sc[2], sc[3]);

  __syncthreads();
  for (int i = threadIdx.x; i < NBP; i += 256)    // coalesced flush
    bhist[(size_t)blockIdx.x * NBP + i] = lh[i];

  red[threadIdx.x] = bmax;
  __syncthreads();
#pragma unroll
  for (int off = 128; off > 0; off >>= 1) {
    if (threadIdx.x < off) red[threadIdx.x] = fmaxf(red[threadIdx.x], red[threadIdx.x + off]);
    __syncthreads();
  }
  if (threadIdx.x == 0) wblockmax[blockIdx.x] = red[0];
}

// ---------------------------------------------------------------------------
// Kernel 2 (8 x 64, ONE wave, zero barriers): per-lane register aggregation
// (lane t owns the 9 bins descending from the top), suffix scan -> exact X,
// C, rem; per-prep-block counts above binX -> exclusive offsets.
// ---------------------------------------------------------------------------
__global__ __launch_bounds__(64) void thresh_kernel(
    const u32* __restrict__ bhist, u32* __restrict__ Xthr, int* __restrict__ Carr,
    int* __restrict__ remv, int* __restrict__ offs)
{
  const int b = blockIdx.x, t = threadIdx.x;
  const u32* base = bhist + (size_t)(b * 64) * NBP;
  const int lo = NBP - t * 9 - 9;            // lane 0 owns the TOP 9 bins

  u32 hb[9] = {0, 0, 0, 0, 0, 0, 0, 0, 0};
  for (int g = 0; g < 64; ++g) {             // 576 independent, pipelined loads
    const u32* hg = base + g * NBP + lo;
#pragma unroll
    for (int q = 0; q < 9; ++q) hb[q] += hg[q];
  }
  int mysum = 0;
#pragma unroll
  for (int q = 0; q < 9; ++q) mysum += (int)hb[q];

  int inc = mysum;                            // suffix-from-top inclusive scan
#pragma unroll
  for (int off = 1; off < 64; off <<= 1) {
    const int v = __shfl_up(inc, off);
    if (t >= off) inc += v;
  }
  const int tot = __shfl(inc, 63);
  const int pre = inc - mysum;

  int Xi = 0, Cv = 0, remV = 0, binXv = 0;
  if (tot < TSEL) {
    if (t == 63) { Xi = (int)(BASE16 << 16); Cv = tot; remV = 0; binXv = 0; }
  } else if (pre < TSEL && inc >= TSEL) {     // unique boundary lane
    int cum = pre, kb = lo, qsel = 8;
    for (int q = 8; q >= 0; --q) {            // top bin of lane-chunk first
      cum += (int)hb[q];
      if (cum >= TSEL) { kb = lo + q; qsel = q; break; }
    }
    int C = cum;
    int Xbin;
    if (C > CAP) { C -= (int)hb[qsel]; Xbin = kb + 1; }   // exclude tie-bin
    else Xbin = kb;
    Xi = (int)((BASE16 + (u32)Xbin) << 16);
    Cv = C; remV = tot - C; binXv = Xbin;
  }
  // broadcast (unique non-zero setter) via wave max-reduce
#pragma unroll
  for (int off = 32; off > 0; off >>= 1) {
    Xi    = max(Xi,    __shfl_xor(Xi, off));
    Cv    = max(Cv,    __shfl_xor(Cv, off));
    remV  = max(remV,  __shfl_xor(remV, off));
    binXv = max(binXv, __shfl_xor(binXv, off));
  }

  // per-prep-block count above binX (lane t = block t), exclusive wave scan
  int cg = 0;
  {
    const u32* hg = base + (size_t)t * NBP;
    for (int bin = binXv; bin < NBP; ++bin) cg += (int)hg[bin];
  }
  int inc2 = cg;
#pragma unroll
  for (int off = 1; off < 64; off <<= 1) {
    const int v = __shfl_up(inc2, off);
    if (t >= off) inc2 += v;
  }
  offs[b * 64 + t] = inc2 - cg;
  if (t == 0) { Xthr[b] = (u32)Xi; Carr[b] = Cv; remv[b] = remV; }
}

// ---------------------------------------------------------------------------
// Kernel 3 (512 x 256): append keys >= X at precomputed per-block offsets.
// LDS counter only; overflow impossible (sum of counts == C <= CAP).
// ---------------------------------------------------------------------------
__global__ __launch_bounds__(256) void compact_kernel(
    const float* __restrict__ wscores, const u32* __restrict__ Xthr,
    const int* __restrict__ offs, u64* __restrict__ keybuf)
{
  const int blk = blockIdx.x;
  const int b = blk >> 6;
  const int n = blk * 256 + threadIdx.x;
  const u32 X = Xthr[b];
  __shared__ int cnt;
  if (threadIdx.x == 0) cnt = 0;
  __syncthreads();
  const int base = b * CAP + offs[blk];

  const float4 v = reinterpret_cast<const float4*>(wscores)[n];
  const float ss[4] = {v.x, v.y, v.z, v.w};
  const int j0 = (n & (P_ - 1)) * 4;
#pragma unroll
  for (int c = 0; c < 4; ++c) {
    if (ss[c] > SCORE_T) {
      const u32 bb = __float_as_uint(ss[c]);
      if (bb >= X) {
        const int pos = atomicAdd(&cnt, 1);   // LDS atomic
        keybuf[base + pos] = ((u64)bb << 16) | (u64)(65535 - (j0 + c));
      }
    }
  }
}

// ---------------------------------------------------------------------------
// Kernel 4 (8 x 512): pure O(CAP). rank sort -> re-decode -> pairwise masks
// -> WAVE-LOCAL greedy fixpoint (wave 0, registers + ballots, no barriers)
// -> gather. Slow-path kept for exactness (never taken on benign data).
// ---------------------------------------------------------------------------
__global__ __launch_bounds__(512) void nms_kernel(
    const float* __restrict__ boxreg, const float* __restrict__ props,
    const int* __restrict__ image_hw,
    const float* __restrict__ wscores, const float* __restrict__ wblockmax,
    const u32* __restrict__ Xthr, const int* __restrict__ remv,
    const int* __restrict__ Carr, const u64* __restrict__ keybuf,
    const float* __restrict__ handside, const float* __restrict__ dxdymag,
    const float* __restrict__ contact, float* __restrict__ out)
{
  const int b = blockIdx.x, t = threadIdx.x;
  const float4* sc4 = reinterpret_cast<const float4*>(wscores) + (size_t)b * (M_ / 4);
  const u32 X = Xthr[b];
  const float Hf = (float)image_hw[0];
  const float Wf = (float)image_hw[1];

  __shared__ float maxv_s;
  __shared__ u64   kall[CAP];
  __shared__ u64   skey[CAP];
  __shared__ float4 cb4[CAP + K_];
  __shared__ float4 cbx[CAP + K_];
  __shared__ float carea[CAP + K_];
  __shared__ float cscf[CAP + K_];
  __shared__ int   cj[CAP + K_];
  __shared__ u64   supmask[CAP * 4];
  __shared__ int   kidx[K_];
  __shared__ int   kcount_s, nslow_s;
  __shared__ u64   red2[512];
  __shared__ u64   bitmap[1024];

  if (t < 64) {
    float v = wblockmax[b * 64 + t];
#pragma unroll
    for (int off = 32; off > 0; off >>= 1) v = fmaxf(v, __shfl_xor(v, off));
    if (t == 0) maxv_s = v;
  }
  if (t == 0) { kcount_s = 0; nslow_s = 0; }
  const int C = min(Carr[b], CAP);
  if (t < CAP) kall[t] = (t < C) ? keybuf[b * CAP + t] : 0ull;
  __syncthreads();
  const float maxv1 = maxv_s + 1.0f;

  // ---- rank-by-counting sort (unique keys, descending) ----
  if (t < CAP) {
    const u64 my = kall[t];
    u32 r = 0;
    for (int u = 0; u < CAP; ++u) r += (kall[u] > my) ? 1u : 0u;
    if (t < C) skey[r] = my;
  }
  __syncthreads();

  // ---- re-decode candidates (bit-identical to reference op order) ----
  if (t < C) {
    const u64 key = skey[t];
    const int j = 65535 - (int)(key & 0xFFFFull);
    const int cls = (j & 3) + 1;
    const int n = b * P_ + (j >> 2);
    const float4 rel = reinterpret_cast<const float4*>(boxreg)[n * 5 + cls];
    const float4 pr  = reinterpret_cast<const float4*>(props)[n];
    const float4 bx = decode_clip(rel, pr, Wf, Hf);
    const float offv = (float)cls * maxv1;
    const float ox1 = bx.x + offv, oy1 = bx.y + offv;
    const float ox2 = bx.z + offv, oy2 = bx.w + offv;
    const int ph = aphys(t);
    cb4[ph] = make_float4(ox1, oy1, ox2, oy2);
    cbx[ph] = bx;
    carea[ph] = (ox2 - ox1) * (oy2 - oy1);
    cscf[ph] = __uint_as_float((u32)(key >> 16));
    cj[ph] = j;
  }
  __syncthreads();

  // ---- pairwise suppression rows (self excluded), 2 tasks/thread ----
  for (int task = t; task < C * 4; task += 512) {
    const int i = task >> 2, wq = task & 3;
    const float4 ib = cb4[aphys(i)];
    const float ia = carea[aphys(i)];
    u64 m = 0;
    const int qb = wq * 64, qe = min(qb + 64, C);
    for (int q = qb; q < qe; ++q) {
      if (q == i) continue;
      const int qp = aphys(q);
      const float4 qbx = cb4[qp];
      const float ltx = fmaxf(ib.x, qbx.x);
      const float lty = fmaxf(ib.y, qbx.y);
      const float rbx = fminf(ib.z, qbx.z);
      const float rby = fminf(ib.w, qbx.w);
      const float iw = fmaxf(rbx - ltx, 0.f);
      const float ih = fmaxf(rby - lty, 0.f);
      const float inter = iw * ih;
      const float iou = inter / (ia + carea[qp] - inter);  // a1+a2-inter
      if (iou > 0.5f) m |= 1ull << (q - qb);               // NaN -> false (ref)
    }
    supmask[i * 4 + wq] = m;
  }
  __syncthreads();

  // ---- WAVE-LOCAL greedy fixpoint: lane t owns rows {t, 64+t, 128+t, 192+t}
  if (t < 64) {
    const u64 lowm = t ? (~0ull >> (64 - t)) : 0ull;
    u64 rb[4][4];
    bool alv[4];
#pragma unroll
    for (int q = 0; q < 4; ++q) {
      const int r = q * 64 + t;
      alv[q] = (r < C);
#pragma unroll
      for (int w = 0; w < 4; ++w) {
        u64 m = supmask[r * 4 + w];
        if (w == q) m &= lowm;                 // suppressors j < r only
        else if (w > q) m = 0ull;
        rb[q][w] = m;
      }
    }
    u64 km0 = __ballot(alv[0]);
    u64 km1 = __ballot(alv[1]);
    u64 km2 = __ballot(alv[2]);
    u64 km3 = __ballot(alv[3]);
    for (int round = 0; round <= CAP; ++round) {
      const bool k0 = alv[0] && !((rb[0][0] & km0) | (rb[0][1] & km1) | (rb[0][2] & km2) | (rb[0][3] & km3));
      const bool k1 = alv[1] && !((rb[1][0] & km0) | (rb[1][1] & km1) | (rb[1][2] & km2) | (rb[1][3] & km3));
      const bool k2 = alv[2] && !((rb[2][0] & km0) | (rb[2][1] & km1) | (rb[2][2] & km2) | (rb[2][3] & km3));
      const bool k3 = alv[3] && !((rb[3][0] & km0) | (rb[3][1] & km1) | (rb[3][2] & km2) | (rb[3][3] & km3));
      const u64 n0 = __ballot(k0);
      const u64 n1 = __ballot(k1);
      const u64 n2 = __ballot(k2);
      const u64 n3 = __ballot(k3);
      if (n0 == km0 && n1 == km1 && n2 == km2 && n3 == km3) break;  // uniform
      km0 = n0; km1 = n1; km2 = n2; km3 = n3;
    }
    // ---- extract keeps in index order (== greedy pop order) ----
#pragma unroll
    for (int q = 0; q < 4; ++q) {
      const u64 kmq = (q == 0) ? km0 : (q == 1) ? km1 : (q == 2) ? km2 : km3;
      if ((kmq >> t) & 1ull) {
        int rank = __popcll(kmq & lowm);
        if (q > 0) rank += __popcll(km0);
        if (q > 1) rank += __popcll(km1);
        if (q > 2) rank += __popcll(km2);
        if (rank < K_) kidx[rank] = q * 64 + t;
      }
    }
    if (t == 0) {
      kcount_s = min(__popcll(km0) + __popcll(km1) +
                     __popcll(km2) + __popcll(km3), K_);
    }
  }
  __syncthreads();

  // ---- slow-path continuation (exactness; skipped on benign data) ----
  if (kcount_s < K_ && remv[b] > 0) {
    for (int i = t; i < 1024; i += 512) bitmap[i] = 0ull;
    __syncthreads();
    while (true) {
      u64 best = 0ull;
      for (int i = t; i < M_ / 4; i += 512) {
        const float4 v = sc4[i];
        const float ss[4] = {v.x, v.y, v.z, v.w};
#pragma unroll
        for (int c = 0; c < 4; ++c) {
          if (ss[c] > SCORE_T) {
            const u32 bb = __float_as_uint(ss[c]);
            if (bb < X) {
              const int j = i * 4 + c;
              if (!((bitmap[j >> 6] >> (j & 63)) & 1ull)) {
                const u64 key = ((u64)bb << 16) | (u64)(65535 - j);
                if (key > best) best = key;
              }
            }
          }
        }
      }
      red2[t] = best;
      __syncthreads();
      for (int off = 256; off > 0; off >>= 1) {
        if (t < off && red2[t + off] > red2[t]) red2[t] = red2[t + off];
        __syncthreads();
      }
      const u64 wkey = red2[0];
      if (wkey == 0ull) break;
      if (t == 0) {
        const int j = 65535 - (int)(wkey & 0xFFFFull);
        bitmap[j >> 6] |= 1ull << (j & 63);
        const int cls = (j & 3) + 1;
        const int n = b * P_ + (j >> 2);
        const float4 rel = reinterpret_cast<const float4*>(boxreg)[n * 5 + cls];
        const float4 pr  = reinterpret_cast<const float4*>(props)[n];
        const float4 bx = decode_clip(rel, pr, Wf, Hf);
        const float offv = (float)cls * maxv1;
        const float ox1 = bx.x + offv, oy1 = bx.y + offv;
        const float ox2 = bx.z + offv, oy2 = bx.w + offv;
        const float ar = (ox2 - ox1) * (oy2 - oy1);
        bool sup = false;
        for (int k2 = 0; k2 < kcount_s; ++k2) {
          const int ki = aphys(kidx[k2]);
          const float4 kb = cb4[ki];
          const float ltx = fmaxf(kb.x, ox1);
          const float lty = fmaxf(kb.y, oy1);
          const float rbx = fminf(kb.z, ox2);
          const float rby = fminf(kb.w, oy2);
          const float iw = fmaxf(rbx - ltx, 0.f);
          const float ih = fmaxf(rby - lty, 0.f);
          const float inter = iw * ih;
          const float iou = inter / (carea[ki] + ar - inter);
          if (iou > 0.5f) { sup = true; break; }
        }
        if (!sup) {
          const int slot = CAP + nslow_s;        // aphys(slot) == slot
          cb4[slot] = make_float4(ox1, oy1, ox2, oy2);
          cbx[slot] = bx;
          carea[slot] = ar;
          cscf[slot] = __uint_as_float((u32)(wkey >> 16));
          cj[slot] = j;
          kidx[kcount_s] = slot;
          ++nslow_s;
          ++kcount_s;
        }
      }
      __syncthreads();
      if (kcount_s >= K_) break;
    }
    __syncthreads();
  }
  __syncthreads();

  // ---- gather outputs ----
  const int kc = kcount_s;
  if (t < K_) {
    const int r = t;
    float ob0 = 0.f, ob1 = 0.f, ob2 = 0.f, ob3 = 0.f;
    float osc = 0.f, olab = 0.f, oside = 0.f;
    float od0 = 0.f, od1 = 0.f, od2 = 0.f;
    float ocon = 0.f, okeep = 0.f;
    if (r < kc) {
      const int idx = kidx[r];
      const int ph = aphys(idx);
      const int j = cj[ph];
      const int cls = (j & 3) + 1;
      const int n = b * P_ + (j >> 2);
      const float4 bx = cbx[ph];                    // unshifted output box
      ob0 = bx.x; ob1 = bx.y; ob2 = bx.z; ob3 = bx.w;
      osc = cscf[ph];
      olab = (float)cls;
      oside = (handside[n * 5 + cls] > 0.f) ? 1.f : 0.f;  // sigmoid>0.5 <=> x>0
      od0 = dxdymag[n * 15 + cls * 3 + 0];
      od1 = dxdymag[n * 15 + cls * 3 + 1];
      od2 = dxdymag[n * 15 + cls * 3 + 2];
      float bvv = contact[n * 25 + cls * 5 + 0];
      int best = 0;
#pragma unroll
      for (int i = 1; i < 5; ++i) {
        const float ci = contact[n * 25 + cls * 5 + i];
        if (ci > bvv) { bvv = ci; best = i; }
      }
      ocon = (float)best;
      okeep = 1.f;
    }
    const int gb = b * K_ + r;
    out[gb * 4 + 0] = ob0;
    out[gb * 4 + 1] = ob1;
    out[gb * 4 + 2] = ob2;
    out[gb * 4 + 3] = ob3;
    out[3200 + gb] = osc;
    out[4000 + gb] = olab;
    out[4800 + gb] = oside;
    out[5600 + gb * 3 + 0] = od0;
    out[5600 + gb * 3 + 1] = od1;
    out[5600 + gb * 3 + 2] = od2;
    out[8000 + gb] = ocon;
    out[8800 + gb] = okeep;
  }
}

// ---------------------------------------------------------------------------
extern "C" void kernel_launch(void* const* d_in, const int* in_sizes, int n_in,
                              void* d_out, int out_size, void* d_ws, size_t ws_size,
                              hipStream_t stream) {
  const float* class_logits = (const float*)d_in[0];
  const float* box_reg      = (const float*)d_in[1];
  const float* handside     = (const float*)d_in[2];
  const float* dxdymag      = (const float*)d_in[3];
  const float* contact      = (const float*)d_in[4];
  const float* proposals    = (const float*)d_in[5];
  const int*   image_hw     = (const int*)d_in[6];
  float* out = (float*)d_out;

  char* ws = (char*)d_ws;
  u32*   bhist     = (u32*)  ws;                       // 512*576*4 = 1179648 B
  u32*   Xthr      = (u32*)  (ws + 1179648);           // 32 B
  int*   Carr      = (int*)  (ws + 1179680);           // 32 B
  int*   remv      = (int*)  (ws + 1179712);           // 32 B
  int*   offs      = (int*)  (ws + 1179776);           // 2048 B
  float* wblockmax = (float*)(ws + 1181824);           // 2048 B
  u64*   keybuf    = (u64*)  (ws + 1183872);           // 16384 B
  float* wscores   = (float*)(ws + 2097152);           // 2 MiB (ends 4 MiB)

  prep_kernel<<<dim3(512), dim3(256), 0, stream>>>(
      class_logits, box_reg, proposals, image_hw, wscores, wblockmax, bhist);
  thresh_kernel<<<dim3(B_), dim3(64), 0, stream>>>(
      bhist, Xthr, Carr, remv, offs);
  compact_kernel<<<dim3(512), dim3(256), 0, stream>>>(
      wscores, Xthr, offs, keybuf);
  nms_kernel<<<dim3(B_), dim3(512), 0, stream>>>(
      box_reg, proposals, image_hw, wscores, wblockmax, Xthr, remv, Carr,
      keybuf, handside, dxdymag, contact, out);
}